// Round 1
// baseline (544.664 us; speedup 1.0000x reference)
//
#include <hip/hip_runtime.h>

typedef float  f32x4  __attribute__((ext_vector_type(4)));
typedef __bf16 bf16x8 __attribute__((ext_vector_type(8)));

#define MFMA_BF16(a, b, c) __builtin_amdgcn_mfma_f32_16x16x32_bf16((a), (b), (c), 0, 0, 0)

// ---------- constants ----------
#define BDIM   4
#define SEQ    2048
#define DM     512
#define NH     8
#define DK     64
#define MROWS  (BDIM * SEQ)          // 8192
#define ATT_SCALE 0.125f
#define NEG_BIG  (-1000000000.0f)

static __device__ __forceinline__ unsigned short f2bf(float f) {
  unsigned int u = __builtin_bit_cast(unsigned int, f);
  u += 0x7fffu + ((u >> 16) & 1u);          // round-to-nearest-even
  return (unsigned short)(u >> 16);
}

// ---------- fp32 -> bf16 convert (vectorized) ----------
__global__ __launch_bounds__(256) void cvt_kernel(const float* __restrict__ src,
                                                  unsigned short* __restrict__ dst, int n4) {
  int i = blockIdx.x * 256 + threadIdx.x;
  if (i >= n4) return;
  float4 v = reinterpret_cast<const float4*>(src)[i];
  ushort4 o;
  o.x = f2bf(v.x); o.y = f2bf(v.y); o.z = f2bf(v.z); o.w = f2bf(v.w);
  reinterpret_cast<ushort4*>(dst)[i] = o;
}

// ---------- mask dtype detection: bool-as-byte vs bool-as-int32 ----------
__global__ void detect_mask_kernel(const unsigned int* __restrict__ m, int* __restrict__ flag) {
  __shared__ int s;
  if (threadIdx.x == 0) s = 0;
  __syncthreads();
  int any = 0;
  for (int i = threadIdx.x; i < 4096; i += 256) any |= (m[i] > 1u) ? 1 : 0;
  if (any) atomicOr(&s, 1);
  __syncthreads();
  if (threadIdx.x == 0) *flag = s;   // 1 => byte storage, 0 => int32 storage
}

// canonicalize mask to uint8 (1 byte per element) in ws
__global__ __launch_bounds__(256) void mask_cvt_kernel(const unsigned char* __restrict__ m8,
                                                       const int* __restrict__ m32,
                                                       const int* __restrict__ flag,
                                                       unsigned char* __restrict__ out) {
  int i = blockIdx.x * 256 + threadIdx.x;   // group of 4 elements
  int use8 = *flag;
  if (use8) {
    reinterpret_cast<uchar4*>(out)[i] = reinterpret_cast<const uchar4*>(m8)[i];
  } else {
    int4 v = reinterpret_cast<const int4*>(m32)[i];
    uchar4 o;
    o.x = (unsigned char)v.x; o.y = (unsigned char)v.y;
    o.z = (unsigned char)v.z; o.w = (unsigned char)v.w;
    reinterpret_cast<uchar4*>(out)[i] = o;
  }
}

// ---------- shared 128x128 bf16 GEMM mainloop: C = A(MxK) * B(NxK)^T ----------
// A row-major [M][K], B row-major [N][K] (both K-contiguous), K multiple of 32.
__device__ __forceinline__ void gemm128_main(const unsigned short* __restrict__ A,
                                             const unsigned short* __restrict__ B,
                                             int K, int row0, int col0,
                                             unsigned short* lds, f32x4 acc[4][4]) {
  const int tid  = threadIdx.x;
  const int w    = tid >> 6;
  const int lane = tid & 63;
  const int lr   = lane & 15;
  const int lk   = (lane >> 4) << 3;
  const int wm   = (w >> 1) << 6;
  const int wn   = (w & 1) << 6;
  const int sr   = tid >> 2;
  const int sc   = (tid & 3) << 3;
  unsigned short* As = lds;              // [128][40]
  unsigned short* Bs = lds + 128 * 40;   // [128][40]
  for (int k0 = 0; k0 < K; k0 += 32) {
    __syncthreads();
    *(int4*)&As[(size_t)sr * 40 + sc]        = *(const int4*)&A[(size_t)(row0 + sr) * K + k0 + sc];
    *(int4*)&As[(size_t)(sr + 64) * 40 + sc] = *(const int4*)&A[(size_t)(row0 + sr + 64) * K + k0 + sc];
    *(int4*)&Bs[(size_t)sr * 40 + sc]        = *(const int4*)&B[(size_t)(col0 + sr) * K + k0 + sc];
    *(int4*)&Bs[(size_t)(sr + 64) * 40 + sc] = *(const int4*)&B[(size_t)(col0 + sr + 64) * K + k0 + sc];
    __syncthreads();
    bf16x8 af[4], bfr[4];
#pragma unroll
    for (int mi = 0; mi < 4; ++mi) af[mi]  = *(const bf16x8*)&As[(size_t)(wm + mi * 16 + lr) * 40 + lk];
#pragma unroll
    for (int ni = 0; ni < 4; ++ni) bfr[ni] = *(const bf16x8*)&Bs[(size_t)(wn + ni * 16 + lr) * 40 + lk];
#pragma unroll
    for (int mi = 0; mi < 4; ++mi)
#pragma unroll
      for (int ni = 0; ni < 4; ++ni)
        acc[mi][ni] = MFMA_BF16(af[mi], bfr[ni], acc[mi][ni]);
  }
}

// ---------- projection GEMM: z picks {Q,K,V}; writes head-major bf16 [B][H][S][64] ----------
__global__ __launch_bounds__(256) void proj_kernel(
    const unsigned short* __restrict__ Xq, const unsigned short* __restrict__ Xk,
    const unsigned short* __restrict__ Xv,
    const unsigned short* __restrict__ Wq, const unsigned short* __restrict__ Wk,
    const unsigned short* __restrict__ Wv,
    unsigned short* __restrict__ Qh, unsigned short* __restrict__ Kh,
    unsigned short* __restrict__ Vh) {
  __shared__ __align__(16) unsigned short lds[2 * 128 * 40];
  const int z = blockIdx.z;
  const unsigned short* A = (z == 0) ? Xq : ((z == 1) ? Xk : Xv);
  const unsigned short* B = (z == 0) ? Wq : ((z == 1) ? Wk : Wv);
  unsigned short* O       = (z == 0) ? Qh : ((z == 1) ? Kh : Vh);
  const int row0 = blockIdx.x * 128, col0 = blockIdx.y * 128;
  f32x4 acc[4][4];
  const f32x4 zero = {0.f, 0.f, 0.f, 0.f};
#pragma unroll
  for (int mi = 0; mi < 4; ++mi)
#pragma unroll
    for (int ni = 0; ni < 4; ++ni) acc[mi][ni] = zero;
  gemm128_main(A, B, DM, row0, col0, lds, acc);
  const int w = threadIdx.x >> 6, lane = threadIdx.x & 63;
  const int lr = lane & 15, lg = lane >> 4;
  const int wm = (w >> 1) << 6, wn = (w & 1) << 6;
#pragma unroll
  for (int mi = 0; mi < 4; ++mi)
#pragma unroll
    for (int ni = 0; ni < 4; ++ni)
#pragma unroll
      for (int j = 0; j < 4; ++j) {
        const int m = row0 + wm + mi * 16 + lg * 4 + j;   // global row in [0,8192)
        const int n = col0 + wn + ni * 16 + lr;           // feature in [0,512)
        const int b = m >> 11, s = m & 2047;
        const int h = n >> 6,  d = n & 63;
        O[(((size_t)(b * NH + h)) * SEQ + s) * DK + d] = f2bf(acc[mi][ni][j]);
      }
}

// ---------- output projection GEMM: fp32 out, flat [8192][512] ----------
__global__ __launch_bounds__(256) void fc_kernel(const unsigned short* __restrict__ A,
                                                 const unsigned short* __restrict__ W,
                                                 float* __restrict__ Out) {
  __shared__ __align__(16) unsigned short lds[2 * 128 * 40];
  const int row0 = blockIdx.x * 128, col0 = blockIdx.y * 128;
  f32x4 acc[4][4];
  const f32x4 zero = {0.f, 0.f, 0.f, 0.f};
#pragma unroll
  for (int mi = 0; mi < 4; ++mi)
#pragma unroll
    for (int ni = 0; ni < 4; ++ni) acc[mi][ni] = zero;
  gemm128_main(A, W, DM, row0, col0, lds, acc);
  const int w = threadIdx.x >> 6, lane = threadIdx.x & 63;
  const int lr = lane & 15, lg = lane >> 4;
  const int wm = (w >> 1) << 6, wn = (w & 1) << 6;
#pragma unroll
  for (int mi = 0; mi < 4; ++mi)
#pragma unroll
    for (int ni = 0; ni < 4; ++ni)
#pragma unroll
      for (int j = 0; j < 4; ++j) {
        const int m = row0 + wm + mi * 16 + lg * 4 + j;
        const int n = col0 + wn + ni * 16 + lr;
        Out[(size_t)m * DM + n] = acc[mi][ni][j];
      }
}

// ---------- QK^T tile (16 q-rows x 64 k-cols per wave) with scale+mask ----------
__device__ __forceinline__ void qk_sv(const unsigned short* __restrict__ Kp,
                                      const unsigned char* __restrict__ mp,
                                      const bf16x8* qf, const int* qrow,
                                      int kt, int lr, int lk, float sv[4][4]) {
#pragma unroll
  for (int ni = 0; ni < 4; ++ni) {
    const unsigned short* kb = Kp + (size_t)(kt + ni * 16 + lr) * DK + lk;
    bf16x8 k0 = *(const bf16x8*)kb;
    bf16x8 k1 = *(const bf16x8*)(kb + 32);
    f32x4 z = {0.f, 0.f, 0.f, 0.f};
    z = MFMA_BF16(qf[0], k0, z);
    z = MFMA_BF16(qf[1], k1, z);
    const int kc = kt + ni * 16 + lr;
#pragma unroll
    for (int j = 0; j < 4; ++j) {
      float s = z[j] * ATT_SCALE;
      sv[ni][j] = mp[(size_t)qrow[j] * SEQ + kc] ? NEG_BIG : s;
    }
  }
}

// ---------- fused attention: scores+softmax+attn-write+PV ----------
// grid: (32 q-tiles, 8 heads, 4 batches), 256 threads (4 waves x 16 q-rows)
__global__ __launch_bounds__(256) void attn_kernel(
    const unsigned short* __restrict__ Qh, const unsigned short* __restrict__ Kh,
    const unsigned short* __restrict__ Vh, const unsigned char* __restrict__ mask8,
    float* __restrict__ attn_out, unsigned short* __restrict__ R16) {
  __shared__ __align__(16) unsigned short Vt[64 * 72];       // V^T tile [d][k]
  __shared__ __align__(16) unsigned short Pl[4 * 16 * 72];   // per-wave P tile [q][k]
  const int qt = blockIdx.x, h = blockIdx.y, b = blockIdx.z;
  const int tid = threadIdx.x, w = tid >> 6, lane = tid & 63;
  const int lr = lane & 15, lg = lane >> 4, lk = lg << 3;
  const size_t headoff = (size_t)(b * NH + h) * SEQ * DK;
  const unsigned short* Qp = Qh + headoff;
  const unsigned short* Kp = Kh + headoff;
  const unsigned short* Vp = Vh + headoff;
  const unsigned char*  mp = mask8 + (size_t)b * SEQ * SEQ;
  float* ap = attn_out + (size_t)(b * NH + h) * SEQ * SEQ;

  const int qb = qt * 64 + w * 16;
  bf16x8 qf[2];
  qf[0] = *(const bf16x8*)(Qp + (size_t)(qb + lr) * DK + lk);
  qf[1] = *(const bf16x8*)(Qp + (size_t)(qb + lr) * DK + 32 + lk);
  int qrow[4];
#pragma unroll
  for (int j = 0; j < 4; ++j) qrow[j] = qb + lg * 4 + j;

  float m_[4] = {-3e38f, -3e38f, -3e38f, -3e38f};
  float l_[4] = {0.f, 0.f, 0.f, 0.f};

  // ---- pass 1: running max / sumexp ----
  for (int kt = 0; kt < SEQ; kt += 64) {
    float sv[4][4];
    qk_sv(Kp, mp, qf, qrow, kt, lr, lk, sv);
#pragma unroll
    for (int j = 0; j < 4; ++j) {
      float t = fmaxf(fmaxf(sv[0][j], sv[1][j]), fmaxf(sv[2][j], sv[3][j]));
      t = fmaxf(t, __shfl_xor(t, 1));
      t = fmaxf(t, __shfl_xor(t, 2));
      t = fmaxf(t, __shfl_xor(t, 4));
      t = fmaxf(t, __shfl_xor(t, 8));
      const float nm = fmaxf(m_[j], t);
      float part = __expf(sv[0][j] - nm) + __expf(sv[1][j] - nm) +
                   __expf(sv[2][j] - nm) + __expf(sv[3][j] - nm);
      part += __shfl_xor(part, 1);
      part += __shfl_xor(part, 2);
      part += __shfl_xor(part, 4);
      part += __shfl_xor(part, 8);
      l_[j] = l_[j] * __expf(m_[j] - nm) + part;
      m_[j] = nm;
    }
  }
  float invl[4];
#pragma unroll
  for (int j = 0; j < 4; ++j) invl[j] = 1.0f / l_[j];

  f32x4 o[4];
  const f32x4 zero = {0.f, 0.f, 0.f, 0.f};
#pragma unroll
  for (int nd = 0; nd < 4; ++nd) o[nd] = zero;
  unsigned short* Pw = Pl + w * 16 * 72;

  // ---- pass 2: recompute S, write attn, accumulate P*V ----
  for (int kt = 0; kt < SEQ; kt += 64) {
    __syncthreads();   // protect Vt reads of previous iteration
#pragma unroll
    for (int it = 0; it < 16; ++it) {
      const int idx = it * 256 + tid;
      const int r = idx >> 6, d = idx & 63;
      Vt[d * 72 + r] = Vp[(size_t)(kt + r) * DK + d];
    }
    __syncthreads();
    float sv[4][4];
    qk_sv(Kp, mp, qf, qrow, kt, lr, lk, sv);
#pragma unroll
    for (int ni = 0; ni < 4; ++ni) {
      const int kc = kt + ni * 16 + lr;
#pragma unroll
      for (int j = 0; j < 4; ++j) {
        float p = __expf(sv[ni][j] - m_[j]) * invl[j];
        p = fminf(fmaxf(p, 1e-8f), 1.0f);
        ap[(size_t)qrow[j] * SEQ + kc] = p;
        Pw[(lg * 4 + j) * 72 + ni * 16 + lr] = f2bf(p);
      }
    }
#pragma unroll
    for (int kk = 0; kk < 2; ++kk) {
      bf16x8 pf = *(const bf16x8*)&Pw[lr * 72 + kk * 32 + lk];
#pragma unroll
      for (int nd = 0; nd < 4; ++nd) {
        bf16x8 vf = *(const bf16x8*)&Vt[(nd * 16 + lr) * 72 + kk * 32 + lk];
        o[nd] = MFMA_BF16(pf, vf, o[nd]);
      }
    }
  }
  // ---- epilogue: write result in [b*S+s][h*64+d] bf16 layout ----
#pragma unroll
  for (int nd = 0; nd < 4; ++nd)
#pragma unroll
    for (int j = 0; j < 4; ++j)
      R16[((size_t)(b * SEQ + qrow[j])) * DM + h * DK + nd * 16 + lr] = f2bf(o[nd][j]);
}

// ---------- residual + LayerNorm (one wave per row) ----------
__global__ __launch_bounds__(256) void ln_kernel(const float* __restrict__ fc,
                                                 const float* __restrict__ xq,
                                                 const float* __restrict__ gamma,
                                                 const float* __restrict__ beta,
                                                 float* __restrict__ out) {
  const int row = blockIdx.x * 4 + (threadIdx.x >> 6);
  const int lane = threadIdx.x & 63;
  const float* f = fc + (size_t)row * DM;
  const float* x = xq + (size_t)row * DM;
  float v[8];
  float s = 0.f, ss = 0.f;
#pragma unroll
  for (int i = 0; i < 8; ++i) {
    const int c = lane + i * 64;
    const float t = f[c] + x[c];
    v[i] = t; s += t; ss += t * t;
  }
#pragma unroll
  for (int off = 1; off < 64; off <<= 1) {
    s  += __shfl_xor(s, off);
    ss += __shfl_xor(ss, off);
  }
  const float mu  = s * (1.f / 512.f);
  const float var = ss * (1.f / 512.f) - mu * mu;
  const float inv = rsqrtf(var + 1e-5f);
  float* op = out + (size_t)row * DM;
#pragma unroll
  for (int i = 0; i < 8; ++i) {
    const int c = lane + i * 64;
    op[c] = (v[i] - mu) * inv * gamma[c] + beta[c];
  }
}

// ---------- workspace layout (bytes) ----------
// phase A: XQ16 0, XK16 8388608, XV16 16777216, WQ16 25165824, WK16 25690112,
//          WV16 26214400, WF16 26738688, Qh 27262976, Kh 35651584, Vh 44040192
// phase B (after proj, X dead):  M8 @0 (16.7MB), R16 @16777216 (8.4MB)
// phase C (after attn, Qh/Kh dead): FC32 @27262976 (16.7MB)
// FLAG @52428800. total ~52.43 MB.

extern "C" void kernel_launch(void* const* d_in, const int* in_sizes, int n_in,
                              void* d_out, int out_size, void* d_ws, size_t ws_size,
                              hipStream_t stream) {
  const float* xq   = (const float*)d_in[0];
  const float* xk   = (const float*)d_in[1];
  const float* xv   = (const float*)d_in[2];
  const void*  mask = d_in[3];
  const float* wq   = (const float*)d_in[4];
  const float* wk   = (const float*)d_in[5];
  const float* wv   = (const float*)d_in[6];
  const float* wfc  = (const float*)d_in[7];
  const float* gamma = (const float*)d_in[8];
  const float* beta  = (const float*)d_in[9];

  float* out = (float*)d_out;
  float* attn_out = out + (size_t)BDIM * SEQ * DM;   // 4,194,304 floats in

  char* ws = (char*)d_ws;
  unsigned short* XQ16 = (unsigned short*)(ws);
  unsigned short* XK16 = (unsigned short*)(ws + 8388608);
  unsigned short* XV16 = (unsigned short*)(ws + 16777216);
  unsigned short* WQ16 = (unsigned short*)(ws + 25165824);
  unsigned short* WK16 = (unsigned short*)(ws + 25690112);
  unsigned short* WV16 = (unsigned short*)(ws + 26214400);
  unsigned short* WF16 = (unsigned short*)(ws + 26738688);
  unsigned short* Qh   = (unsigned short*)(ws + 27262976);
  unsigned short* Kh   = (unsigned short*)(ws + 35651584);
  unsigned short* Vh   = (unsigned short*)(ws + 44040192);
  unsigned char*  M8   = (unsigned char*)(ws);                 // reuse XQ16/XK16
  unsigned short* R16  = (unsigned short*)(ws + 16777216);     // reuse XV16
  float*          FC32 = (float*)(ws + 27262976);              // reuse Qh/Kh
  int*            FLAG = (int*)(ws + 52428800);

  const int NX4 = BDIM * SEQ * DM / 4;   // 1,048,576
  const int NW4 = DM * DM / 4;           // 65,536
  const int NM4 = BDIM * SEQ * SEQ / 4;  // 4,194,304

  detect_mask_kernel<<<1, 256, 0, stream>>>((const unsigned int*)mask, FLAG);
  cvt_kernel<<<NX4 / 256, 256, 0, stream>>>(xq,  XQ16, NX4);
  cvt_kernel<<<NX4 / 256, 256, 0, stream>>>(xk,  XK16, NX4);
  cvt_kernel<<<NX4 / 256, 256, 0, stream>>>(xv,  XV16, NX4);
  cvt_kernel<<<NW4 / 256, 256, 0, stream>>>(wq,  WQ16, NW4);
  cvt_kernel<<<NW4 / 256, 256, 0, stream>>>(wk,  WK16, NW4);
  cvt_kernel<<<NW4 / 256, 256, 0, stream>>>(wv,  WV16, NW4);
  cvt_kernel<<<NW4 / 256, 256, 0, stream>>>(wfc, WF16, NW4);
  proj_kernel<<<dim3(64, 4, 3), 256, 0, stream>>>(XQ16, XK16, XV16,
                                                  WQ16, WK16, WV16, Qh, Kh, Vh);
  mask_cvt_kernel<<<NM4 / 256, 256, 0, stream>>>((const unsigned char*)mask,
                                                 (const int*)mask, FLAG, M8);
  attn_kernel<<<dim3(32, 8, 4), 256, 0, stream>>>(Qh, Kh, Vh, M8, attn_out, R16);
  fc_kernel<<<dim3(64, 4, 1), 256, 0, stream>>>(R16, WF16, FC32);
  ln_kernel<<<2048, 256, 0, stream>>>(FC32, xq, gamma, beta, out);
}

// Round 4
// 530.742 us; speedup vs baseline: 1.0262x; 1.0262x over previous
//
#include <hip/hip_runtime.h>

typedef float  f32x4  __attribute__((ext_vector_type(4)));
typedef __bf16 bf16x8 __attribute__((ext_vector_type(8)));

#define MFMA_BF16(a, b, c) __builtin_amdgcn_mfma_f32_16x16x32_bf16((a), (b), (c), 0, 0, 0)

// ---------- constants ----------
#define BDIM   4
#define SEQ    2048
#define DM     512
#define NH     8
#define DK     64
#define ATT_SCALE 0.125f
#define NEG_CAP  (-80.0f)   // masked score; exp(-80)~2e-35: sum stays normal, all-masked rows uniform
#define KT     64           // k-tile
#define NT     (SEQ / KT)   // 32
#define QB     128          // q-rows per block (8 waves x 16)
#define PS     72           // P-tile LDS stride (shorts)

static __device__ __forceinline__ unsigned short f2bf(float f) {
  unsigned int u = __builtin_bit_cast(unsigned int, f);
  u += 0x7fffu + ((u >> 16) & 1u);   // round-to-nearest-even
  return (unsigned short)(u >> 16);
}

// ---------- fp32 -> bf16 convert ----------
__global__ __launch_bounds__(256) void cvt_kernel(const float* __restrict__ src,
                                                  unsigned short* __restrict__ dst, int n4) {
  int i = blockIdx.x * 256 + threadIdx.x;
  if (i >= n4) return;
  float4 v = reinterpret_cast<const float4*>(src)[i];
  ushort4 o;
  o.x = f2bf(v.x); o.y = f2bf(v.y); o.z = f2bf(v.z); o.w = f2bf(v.w);
  reinterpret_cast<ushort4*>(dst)[i] = o;
}

// ---------- mask dtype detection: bool-as-byte vs bool-as-int32 ----------
__global__ void detect_mask_kernel(const unsigned int* __restrict__ m, int* __restrict__ flag) {
  __shared__ int s;
  if (threadIdx.x == 0) s = 0;
  __syncthreads();
  int any = 0;
  for (int i = threadIdx.x; i < 4096; i += 256) any |= (m[i] > 1u) ? 1 : 0;
  if (any) atomicOr(&s, 1);
  __syncthreads();
  if (threadIdx.x == 0) *flag = s;   // 1 => byte storage, 0 => int32 storage
}

// ---------- pack mask to bits: word w covers flat row r = w/32, cols [(w%32)*64, +64) ----------
__global__ __launch_bounds__(256) void mask_pack_kernel(const unsigned char* __restrict__ m8,
                                                        const int* __restrict__ m32,
                                                        const int* __restrict__ flag,
                                                        unsigned long long* __restrict__ bits) {
  const int wid = blockIdx.x * 256 + threadIdx.x;   // 0..262143
  const int use8 = *flag;
  unsigned long long v = 0;
  if (use8) {
    const uchar4* p = (const uchar4*)(m8 + (size_t)wid * 64);
#pragma unroll
    for (int c = 0; c < 16; ++c) {
      uchar4 q = p[c];
      v |= ((unsigned long long)(q.x != 0)) << (c * 4 + 0);
      v |= ((unsigned long long)(q.y != 0)) << (c * 4 + 1);
      v |= ((unsigned long long)(q.z != 0)) << (c * 4 + 2);
      v |= ((unsigned long long)(q.w != 0)) << (c * 4 + 3);
    }
  } else {
    // FIX(R3->R4): word wid covers ELEMENTS [wid*64, wid*64+64) -> ints at m32 + wid*64
    const int4* p = (const int4*)(m32 + (size_t)wid * 64);
#pragma unroll
    for (int c = 0; c < 16; ++c) {
      int4 q = p[c];
      v |= ((unsigned long long)(q.x != 0)) << (c * 4 + 0);
      v |= ((unsigned long long)(q.y != 0)) << (c * 4 + 1);
      v |= ((unsigned long long)(q.z != 0)) << (c * 4 + 2);
      v |= ((unsigned long long)(q.w != 0)) << (c * 4 + 3);
    }
  }
  bits[wid] = v;
}

// ---------- shared 128x128 bf16 GEMM mainloop: C = A(MxK) * B(NxK)^T ----------
__device__ __forceinline__ void gemm128_main(const unsigned short* __restrict__ A,
                                             const unsigned short* __restrict__ B,
                                             int K, int row0, int col0,
                                             unsigned short* lds, f32x4 acc[4][4]) {
  const int tid  = threadIdx.x;
  const int w    = tid >> 6;
  const int lane = tid & 63;
  const int lr   = lane & 15;
  const int lk   = (lane >> 4) << 3;
  const int wm   = (w >> 1) << 6;
  const int wn   = (w & 1) << 6;
  const int sr   = tid >> 2;
  const int sc   = (tid & 3) << 3;
  unsigned short* As = lds;
  unsigned short* Bs = lds + 128 * 40;
  for (int k0 = 0; k0 < K; k0 += 32) {
    __syncthreads();
    *(int4*)&As[(size_t)sr * 40 + sc]        = *(const int4*)&A[(size_t)(row0 + sr) * K + k0 + sc];
    *(int4*)&As[(size_t)(sr + 64) * 40 + sc] = *(const int4*)&A[(size_t)(row0 + sr + 64) * K + k0 + sc];
    *(int4*)&Bs[(size_t)sr * 40 + sc]        = *(const int4*)&B[(size_t)(col0 + sr) * K + k0 + sc];
    *(int4*)&Bs[(size_t)(sr + 64) * 40 + sc] = *(const int4*)&B[(size_t)(col0 + sr + 64) * K + k0 + sc];
    __syncthreads();
    bf16x8 af[4], bfr[4];
#pragma unroll
    for (int mi = 0; mi < 4; ++mi) af[mi]  = *(const bf16x8*)&As[(size_t)(wm + mi * 16 + lr) * 40 + lk];
#pragma unroll
    for (int ni = 0; ni < 4; ++ni) bfr[ni] = *(const bf16x8*)&Bs[(size_t)(wn + ni * 16 + lr) * 40 + lk];
#pragma unroll
    for (int mi = 0; mi < 4; ++mi)
#pragma unroll
      for (int ni = 0; ni < 4; ++ni)
        acc[mi][ni] = MFMA_BF16(af[mi], bfr[ni], acc[mi][ni]);
  }
}

// ---------- projection GEMM: z in {Q,K,V}. Q/K write [b,h,s,d]; V writes TRANSPOSED [b,h,d,s] ----------
__global__ __launch_bounds__(256) void proj_kernel(
    const unsigned short* __restrict__ Xq, const unsigned short* __restrict__ Xk,
    const unsigned short* __restrict__ Xv,
    const unsigned short* __restrict__ Wq, const unsigned short* __restrict__ Wk,
    const unsigned short* __restrict__ Wv,
    unsigned short* __restrict__ Qh, unsigned short* __restrict__ Kh,
    unsigned short* __restrict__ VT) {
  __shared__ __align__(16) unsigned short lds[2 * 128 * 40];
  const int z = blockIdx.z;
  const unsigned short* A = (z == 0) ? Xq : ((z == 1) ? Xk : Xv);
  const unsigned short* B = (z == 0) ? Wq : ((z == 1) ? Wk : Wv);
  unsigned short* O       = (z == 0) ? Qh : ((z == 1) ? Kh : VT);
  const int row0 = blockIdx.x * 128, col0 = blockIdx.y * 128;
  f32x4 acc[4][4];
  const f32x4 zero = {0.f, 0.f, 0.f, 0.f};
#pragma unroll
  for (int mi = 0; mi < 4; ++mi)
#pragma unroll
    for (int ni = 0; ni < 4; ++ni) acc[mi][ni] = zero;
  gemm128_main(A, B, DM, row0, col0, lds, acc);
  const int w = threadIdx.x >> 6, lane = threadIdx.x & 63;
  const int lr = lane & 15, lg = lane >> 4;
  const int wm = (w >> 1) << 6, wn = (w & 1) << 6;
#pragma unroll
  for (int mi = 0; mi < 4; ++mi)
#pragma unroll
    for (int ni = 0; ni < 4; ++ni)
#pragma unroll
      for (int j = 0; j < 4; ++j) {
        const int m = row0 + wm + mi * 16 + lg * 4 + j;   // global row in [0,8192)
        const int n = col0 + wn + ni * 16 + lr;           // feature in [0,512)
        const int b = m >> 11, s = m & 2047;
        const int h = n >> 6,  d = n & 63;
        const unsigned short val = f2bf(acc[mi][ni][j]);
        if (z == 2)
          O[(((size_t)(b * NH + h)) * DK + d) * SEQ + s] = val;   // V^T: [b,h,d,s]
        else
          O[(((size_t)(b * NH + h)) * SEQ + s) * DK + d] = val;   // [b,h,s,d]
      }
}

// ---------- output projection GEMM: fp32 out, flat [8192][512] ----------
__global__ __launch_bounds__(256) void fc_kernel(const unsigned short* __restrict__ A,
                                                 const unsigned short* __restrict__ W,
                                                 float* __restrict__ Out) {
  __shared__ __align__(16) unsigned short lds[2 * 128 * 40];
  const int row0 = blockIdx.x * 128, col0 = blockIdx.y * 128;
  f32x4 acc[4][4];
  const f32x4 zero = {0.f, 0.f, 0.f, 0.f};
#pragma unroll
  for (int mi = 0; mi < 4; ++mi)
#pragma unroll
    for (int ni = 0; ni < 4; ++ni) acc[mi][ni] = zero;
  gemm128_main(A, W, DM, row0, col0, lds, acc);
  const int w = threadIdx.x >> 6, lane = threadIdx.x & 63;
  const int lr = lane & 15, lg = lane >> 4;
  const int wm = (w >> 1) << 6, wn = (w & 1) << 6;
#pragma unroll
  for (int mi = 0; mi < 4; ++mi)
#pragma unroll
    for (int ni = 0; ni < 4; ++ni)
#pragma unroll
      for (int j = 0; j < 4; ++j) {
        const int m = row0 + wm + mi * 16 + lg * 4 + j;
        const int n = col0 + wn + ni * 16 + lr;
        Out[(size_t)m * DM + n] = acc[mi][ni][j];
      }
}

// ---------- QK^T tile: 16 q-rows x 64 k-cols per wave, K direct from global (L2/L1-hot) ----------
__device__ __forceinline__ void qk_tile(const unsigned short* __restrict__ Kt,  // Kp + t*KT*DK
                                        const unsigned long long mrow[4],
                                        bf16x8 qf0, bf16x8 qf1,
                                        int lr, int lg, float sv[4][4]) {
#pragma unroll
  for (int ni = 0; ni < 4; ++ni) {
    const unsigned short* kb = Kt + (size_t)(ni * 16 + lr) * DK + lg * 8;
    bf16x8 k0 = *(const bf16x8*)kb;
    bf16x8 k1 = *(const bf16x8*)(kb + 32);
    f32x4 z = {0.f, 0.f, 0.f, 0.f};
    z = MFMA_BF16(qf0, k0, z);
    z = MFMA_BF16(qf1, k1, z);
#pragma unroll
    for (int j = 0; j < 4; ++j) {
      const float s = z[j] * ATT_SCALE;
      const unsigned m = (unsigned)(mrow[j] >> (ni * 16 + lr)) & 1u;
      sv[ni][j] = m ? NEG_CAP : s;
    }
  }
}

// ---------- fused attention: scores+softmax+attn-write+PV ----------
// grid (16, 8, 4) remapped XCD-aware; 512 threads = 8 independent waves x 16 q-rows
__global__ __launch_bounds__(512, 4) void attn_kernel(
    const unsigned short* __restrict__ Qh, const unsigned short* __restrict__ Kh,
    const unsigned short* __restrict__ VT, const unsigned long long* __restrict__ Mb,
    float* __restrict__ attn_out, unsigned short* __restrict__ R16) {
  __shared__ __align__(16) unsigned short Pl[8][16 * PS];
  // XCD-aware remap: all 16 q-tiles of one (b,h) land on the same XCD (id%8 fixed)
  const int id  = blockIdx.x + 16 * (blockIdx.y + 8 * blockIdx.z);   // 0..511
  const int q8  = id >> 3;
  const int bh  = (id & 7) * 4 + (q8 >> 4);   // 0..31
  const int qt  = q8 & 15;                    // 0..15
  const int b   = bh >> 3;
  const int tid = threadIdx.x, w = tid >> 6, lane = tid & 63;
  const int lr = lane & 15, lg = lane >> 4;
  const unsigned short* Qp = Qh + (size_t)bh * SEQ * DK;
  const unsigned short* Kp = Kh + (size_t)bh * SEQ * DK;
  const unsigned short* Vp = VT + (size_t)bh * DK * SEQ;   // [d][s]
  const unsigned long long* mb = Mb + (size_t)b * SEQ * 32;
  float* ap = attn_out + (size_t)bh * SEQ * SEQ;

  const int qb = qt * QB + w * 16;
  const bf16x8 qf0 = *(const bf16x8*)(Qp + (size_t)(qb + lr) * DK + lg * 8);
  const bf16x8 qf1 = *(const bf16x8*)(Qp + (size_t)(qb + lr) * DK + 32 + lg * 8);
  int qrow[4];
#pragma unroll
  for (int j = 0; j < 4; ++j) qrow[j] = qb + lg * 4 + j;

  // ================= pass 1: row sums (fixed-max softmax) =================
  float l_[4] = {0.f, 0.f, 0.f, 0.f};
  for (int t = 0; t < NT; ++t) {
    unsigned long long mrow[4];
#pragma unroll
    for (int j = 0; j < 4; ++j) mrow[j] = mb[(size_t)qrow[j] * 32 + t];
    float sv[4][4];
    qk_tile(Kp + (size_t)t * KT * DK, mrow, qf0, qf1, lr, lg, sv);
#pragma unroll
    for (int j = 0; j < 4; ++j)
      l_[j] += __expf(sv[0][j]) + __expf(sv[1][j]) + __expf(sv[2][j]) + __expf(sv[3][j]);
  }
  float invl[4];
#pragma unroll
  for (int j = 0; j < 4; ++j) {
    float l = l_[j];
    l += __shfl_xor(l, 1);
    l += __shfl_xor(l, 2);
    l += __shfl_xor(l, 4);
    l += __shfl_xor(l, 8);
    invl[j] = 1.0f / l;
  }

  // ================= pass 2: P write + PV =================
  f32x4 o[4];
  const f32x4 zero = {0.f, 0.f, 0.f, 0.f};
#pragma unroll
  for (int nd = 0; nd < 4; ++nd) o[nd] = zero;
  unsigned short* Pw = &Pl[w][0];

  for (int t = 0; t < NT; ++t) {
    unsigned long long mrow[4];
#pragma unroll
    for (int j = 0; j < 4; ++j) mrow[j] = mb[(size_t)qrow[j] * 32 + t];
    float sv[4][4];
    qk_tile(Kp + (size_t)t * KT * DK, mrow, qf0, qf1, lr, lg, sv);
#pragma unroll
    for (int ni = 0; ni < 4; ++ni)
#pragma unroll
      for (int j = 0; j < 4; ++j) {
        float p = __expf(sv[ni][j]) * invl[j];
        p = fminf(fmaxf(p, 1e-8f), 1.0f);
        ap[(size_t)qrow[j] * SEQ + t * KT + ni * 16 + lr] = p;   // 4x64B segments/instr
        Pw[(lg * 4 + j) * PS + ni * 16 + lr] = f2bf(p);
      }
    // --- PV: A = P rows from LDS, B = V^T rows from global (L2/L1-hot) ---
#pragma unroll
    for (int kk = 0; kk < 2; ++kk) {
      const bf16x8 pf = *(const bf16x8*)&Pw[lr * PS + kk * 32 + lg * 8];
#pragma unroll
      for (int nd = 0; nd < 4; ++nd) {
        const bf16x8 vf = *(const bf16x8*)&Vp[(size_t)(nd * 16 + lr) * SEQ + t * KT + kk * 32 + lg * 8];
        o[nd] = MFMA_BF16(pf, vf, o[nd]);
      }
    }
  }
  // ---- epilogue: write result in [b*S+s][h*64+d] bf16 layout ----
#pragma unroll
  for (int nd = 0; nd < 4; ++nd)
#pragma unroll
    for (int j = 0; j < 4; ++j)
      R16[((size_t)(b * SEQ + qrow[j])) * DM + (bh & 7) * DK + nd * 16 + lr] = f2bf(o[nd][j]);
}

// ---------- residual + LayerNorm (one wave per row) ----------
__global__ __launch_bounds__(256) void ln_kernel(const float* __restrict__ fc,
                                                 const float* __restrict__ xq,
                                                 const float* __restrict__ gamma,
                                                 const float* __restrict__ beta,
                                                 float* __restrict__ out) {
  const int row = blockIdx.x * 4 + (threadIdx.x >> 6);
  const int lane = threadIdx.x & 63;
  const float* f = fc + (size_t)row * DM;
  const float* x = xq + (size_t)row * DM;
  float v[8];
  float s = 0.f, ss = 0.f;
#pragma unroll
  for (int i = 0; i < 8; ++i) {
    const int c = lane + i * 64;
    const float t = f[c] + x[c];
    v[i] = t; s += t; ss += t * t;
  }
#pragma unroll
  for (int off = 1; off < 64; off <<= 1) {
    s  += __shfl_xor(s, off);
    ss += __shfl_xor(ss, off);
  }
  const float mu  = s * (1.f / 512.f);
  const float var = ss * (1.f / 512.f) - mu * mu;
  const float inv = rsqrtf(var + 1e-5f);
  float* op = out + (size_t)row * DM;
#pragma unroll
  for (int i = 0; i < 8; ++i) {
    const int c = lane + i * 64;
    op[c] = (v[i] - mu) * inv * gamma[c] + beta[c];
  }
}

// ---------- workspace layout (bytes) ----------
// phase A: XQ16 0, XK16 8388608, XV16 16777216, WQ16 25165824, WK16 25690112,
//          WV16 26214400, WF16 26738688, Qh 27262976, Kh 35651584, VT 44040192
// phase B (X dead): Mbits @0 (2MB), R16 @16777216 (8.4MB)
// phase C (Qh/Kh dead): FC32 @27262976 (16.7MB). FLAG @52428800.

extern "C" void kernel_launch(void* const* d_in, const int* in_sizes, int n_in,
                              void* d_out, int out_size, void* d_ws, size_t ws_size,
                              hipStream_t stream) {
  const float* xq   = (const float*)d_in[0];
  const float* xk   = (const float*)d_in[1];
  const float* xv   = (const float*)d_in[2];
  const void*  mask = d_in[3];
  const float* wq   = (const float*)d_in[4];
  const float* wk   = (const float*)d_in[5];
  const float* wv   = (const float*)d_in[6];
  const float* wfc  = (const float*)d_in[7];
  const float* gamma = (const float*)d_in[8];
  const float* beta  = (const float*)d_in[9];

  float* out = (float*)d_out;
  float* attn_out = out + (size_t)BDIM * SEQ * DM;

  char* ws = (char*)d_ws;
  unsigned short* XQ16 = (unsigned short*)(ws);
  unsigned short* XK16 = (unsigned short*)(ws + 8388608);
  unsigned short* XV16 = (unsigned short*)(ws + 16777216);
  unsigned short* WQ16 = (unsigned short*)(ws + 25165824);
  unsigned short* WK16 = (unsigned short*)(ws + 25690112);
  unsigned short* WV16 = (unsigned short*)(ws + 26214400);
  unsigned short* WF16 = (unsigned short*)(ws + 26738688);
  unsigned short* Qh   = (unsigned short*)(ws + 27262976);
  unsigned short* Kh   = (unsigned short*)(ws + 35651584);
  unsigned short* VT   = (unsigned short*)(ws + 44040192);
  unsigned long long* Mbits = (unsigned long long*)(ws);        // reuse XQ16 (2MB)
  unsigned short* R16  = (unsigned short*)(ws + 16777216);      // reuse XV16
  float*          FC32 = (float*)(ws + 27262976);               // reuse Qh/Kh
  int*            FLAG = (int*)(ws + 52428800);

  const int NX4 = BDIM * SEQ * DM / 4;
  const int NW4 = DM * DM / 4;

  detect_mask_kernel<<<1, 256, 0, stream>>>((const unsigned int*)mask, FLAG);
  cvt_kernel<<<NX4 / 256, 256, 0, stream>>>(xq,  XQ16, NX4);
  cvt_kernel<<<NX4 / 256, 256, 0, stream>>>(xk,  XK16, NX4);
  cvt_kernel<<<NX4 / 256, 256, 0, stream>>>(xv,  XV16, NX4);
  cvt_kernel<<<NW4 / 256, 256, 0, stream>>>(wq,  WQ16, NW4);
  cvt_kernel<<<NW4 / 256, 256, 0, stream>>>(wk,  WK16, NW4);
  cvt_kernel<<<NW4 / 256, 256, 0, stream>>>(wv,  WV16, NW4);
  cvt_kernel<<<NW4 / 256, 256, 0, stream>>>(wfc, WF16, NW4);
  proj_kernel<<<dim3(64, 4, 3), 256, 0, stream>>>(XQ16, XK16, XV16,
                                                  WQ16, WK16, WV16, Qh, Kh, VT);
  mask_pack_kernel<<<1024, 256, 0, stream>>>((const unsigned char*)mask,
                                             (const int*)mask, FLAG, Mbits);
  attn_kernel<<<dim3(16, NH, BDIM), 512, 0, stream>>>(Qh, Kh, VT, Mbits, attn_out, R16);
  fc_kernel<<<dim3(64, 4, 1), 256, 0, stream>>>(R16, WF16, FC32);
  ln_kernel<<<2048, 256, 0, stream>>>(FC32, xq, gamma, beta, out);
}